// Round 4
// baseline (2181.464 us; speedup 1.0000x reference)
//
#include <hip/hip_runtime.h>
#include <math.h>

typedef unsigned short u16;
typedef __attribute__((ext_vector_type(8))) short short8;
typedef __attribute__((ext_vector_type(4))) float floatx4;

#define Hh 16
#define Mm 1024
#define Dd 512
#define Oo 512
#define Nn 16384

__device__ __forceinline__ float b2f(u16 u) { return __uint_as_float(((unsigned)u) << 16); }
__device__ __forceinline__ u16 f2b(float f) {
    unsigned v = __float_as_uint(f);
    v += 0x7fffu + ((v >> 16) & 1u);
    return (u16)(v >> 16);
}
__device__ __forceinline__ short8 cvt8(const float* p) {
    float4 a = *(const float4*)p, b = *(const float4*)(p + 4);
    u16 o[8];
    o[0] = f2b(a.x); o[1] = f2b(a.y); o[2] = f2b(a.z); o[3] = f2b(a.w);
    o[4] = f2b(b.x); o[5] = f2b(b.y); o[6] = f2b(b.z); o[7] = f2b(b.w);
    return *(short8*)o;
}

// ---------------------------------------------------------------------------
// Generic GEMM-BT: C[h][m][n] = sum_k A[h][m][k] * B[h][n][k] (+ bias[h][n])
// ---------------------------------------------------------------------------
__global__ __launch_bounds__(256) void gemm_bt(
    const void* __restrict__ A, const void* __restrict__ B, const float* __restrict__ bias,
    void* __restrict__ C, int K, int lda, int ldb, int ldc,
    long sA, long sB, long sBias, long sC, int aF32, int bF32, int outBf)
{
    __shared__ u16 At[64][72];
    __shared__ u16 Bt[64][72];
    const int tid = threadIdx.x, lane = tid & 63, wid = tid >> 6;
    const int m0 = blockIdx.y * 64, n0 = blockIdx.x * 64;
    const int h = blockIdx.z;
    const int wm = wid >> 1, wn = wid & 1;
    const int rl = lane & 15, rq = (lane >> 4) * 4, gl8 = (lane >> 4) * 8;

    floatx4 zero4 = {0.f, 0.f, 0.f, 0.f};
    floatx4 acc[2][2];
    acc[0][0] = zero4; acc[0][1] = zero4; acc[1][0] = zero4; acc[1][1] = zero4;

    for (int k0 = 0; k0 < K; k0 += 64) {
#pragma unroll
        for (int i = 0; i < 2; i++) {
            int c = tid + i * 256;
            int r = c >> 3, cc = (c & 7) * 8;
            long aoff = (long)h * sA + (long)(m0 + r) * lda + k0 + cc;
            long boff = (long)h * sB + (long)(n0 + r) * ldb + k0 + cc;
            *(short8*)&At[r][cc] = aF32 ? cvt8((const float*)A + aoff)
                                        : *(const short8*)((const u16*)A + aoff);
            *(short8*)&Bt[r][cc] = bF32 ? cvt8((const float*)B + boff)
                                        : *(const short8*)((const u16*)B + boff);
        }
        __syncthreads();
#pragma unroll
        for (int ks = 0; ks < 2; ks++) {
            short8 a0 = *(const short8*)&At[wm * 32 + rl][ks * 32 + gl8];
            short8 a1 = *(const short8*)&At[wm * 32 + 16 + rl][ks * 32 + gl8];
            short8 b0 = *(const short8*)&Bt[wn * 32 + rl][ks * 32 + gl8];
            short8 b1 = *(const short8*)&Bt[wn * 32 + 16 + rl][ks * 32 + gl8];
            acc[0][0] = __builtin_amdgcn_mfma_f32_16x16x32_bf16(a0, b0, acc[0][0], 0, 0, 0);
            acc[0][1] = __builtin_amdgcn_mfma_f32_16x16x32_bf16(a0, b1, acc[0][1], 0, 0, 0);
            acc[1][0] = __builtin_amdgcn_mfma_f32_16x16x32_bf16(a1, b0, acc[1][0], 0, 0, 0);
            acc[1][1] = __builtin_amdgcn_mfma_f32_16x16x32_bf16(a1, b1, acc[1][1], 0, 0, 0);
        }
        __syncthreads();
    }

#pragma unroll
    for (int i = 0; i < 2; i++)
#pragma unroll
        for (int j = 0; j < 2; j++) {
            int col = n0 + wn * 32 + j * 16 + rl;
            float bb = bias ? bias[(long)h * sBias + col] : 0.f;
#pragma unroll
            for (int r = 0; r < 4; r++) {
                int row = m0 + wm * 32 + i * 16 + rq + r;
                long idx = (long)h * sC + (long)row * ldc + col;
                float v = acc[i][j][r] + bb;
                if (outBf) ((u16*)C)[idx] = f2b(v);
                else       ((float*)C)[idx] = v;
            }
        }
}

// ---------------------------------------------------------------------------
// Row softmax: rows of 512 fp32 logits -> bf16 probabilities. One wave/row.
// ---------------------------------------------------------------------------
__global__ __launch_bounds__(256) void softmax_rows(const float* __restrict__ L, u16* __restrict__ Kout)
{
    const int tid = threadIdx.x, lane = tid & 63, wid = tid >> 6;
    const long row = (long)blockIdx.x * 4 + wid;
    const float* p = L + row * 512 + lane * 8;
    float v[8];
    *(float4*)&v[0] = *(const float4*)p;
    *(float4*)&v[4] = *(const float4*)(p + 4);
    float mx = v[0];
#pragma unroll
    for (int i = 1; i < 8; i++) mx = fmaxf(mx, v[i]);
    for (int d = 1; d < 64; d <<= 1) mx = fmaxf(mx, __shfl_xor(mx, d));
    float s = 0.f;
#pragma unroll
    for (int i = 0; i < 8; i++) { v[i] = __expf(v[i] - mx); s += v[i]; }
    for (int d = 1; d < 64; d <<= 1) s += __shfl_xor(s, d);
    float inv = 1.f / s;
    u16 o[8];
#pragma unroll
    for (int i = 0; i < 8; i++) o[i] = f2b(v[i] * inv);
    *(short8*)(Kout + row * 512 + lane * 8) = *(short8*)o;
}

// ---------------------------------------------------------------------------
// Fused flash attention over heads. 32 queries/block, 1024 threads (16 waves),
// full-head S (P[32][1024]) -> exact l -> normalize pass -> PV. Direct-global
// B-fragments for key and V'. Final projection pre-folded into V'.
// ---------------------------------------------------------------------------
#define LDQ 520     // Q row stride u16: 260 dw == 4 mod 32 -> balanced b128 reads
#define LDP 1032    // P row stride u16: 516 dw == 4 mod 32 -> balanced b128 reads
#define FLASH_LDS ((32 * LDQ + 32 * LDP) * 2 + 2 * 32 * 4 + 16)

__global__ __launch_bounds__(1024) void flash(
    const float* __restrict__ kq, const u16* __restrict__ key,
    const u16* __restrict__ vpt, const float* __restrict__ bfv, float* __restrict__ out)
{
    extern __shared__ u16 sm[];
    u16* kq_s = sm;                               // [32][LDQ]
    u16* P = sm + 32 * LDQ;                       // [32][LDP]
    float* lbuf = (float*)(sm + 32 * (LDQ + LDP)); // [2][32]

    const int tid = threadIdx.x, lane = tid & 63, wid = tid >> 6;
    const int n0 = blockIdx.x * 32;
    const int rl = lane & 15, rq = (lane >> 4) * 4, gl8 = (lane >> 4) * 8;

    // load+convert query tile [32][512] fp32 -> bf16 LDS (wave-contiguous rows)
#pragma unroll
    for (int i = 0; i < 2; i++) {
        int c = tid + i * 1024;
        int r = c >> 6, cc = (c & 63) * 8;
        *(short8*)&kq_s[r * LDQ + cc] = cvt8(&kq[(long)(n0 + r) * 512 + cc]);
    }
    if (tid < 64) lbuf[tid] = 0.f;
    __syncthreads();

    floatx4 zero4 = {0.f, 0.f, 0.f, 0.f};
    floatx4 oacc[2][2];
    oacc[0][0] = zero4; oacc[0][1] = zero4; oacc[1][0] = zero4; oacc[1][1] = zero4;

    for (int h = 0; h < Hh; h++) {
        const u16* keyh = key + (long)h * Mm * Oo;
        const u16* vph = vpt + (long)h * Oo * Mm;
        float* lcur = lbuf + (h & 1) * 32;
        float* lnxt = lbuf + ((h + 1) & 1) * 32;

        // ---- S phase: wave owns m-rows [wid*64, +64) of the full head ----
        {
            const int m0 = wid * 64;
            const u16* bp = keyh + (long)(m0 + rl) * 512 + gl8;
            floatx4 s[2][4];
#pragma unroll
            for (int qt = 0; qt < 2; qt++)
#pragma unroll
                for (int t = 0; t < 4; t++) s[qt][t] = zero4;

#pragma unroll 4
            for (int ks = 0; ks < 16; ks++) {
                short8 a0 = *(const short8*)&kq_s[rl * LDQ + ks * 32 + gl8];
                short8 a1 = *(const short8*)&kq_s[(16 + rl) * LDQ + ks * 32 + gl8];
#pragma unroll
                for (int t = 0; t < 4; t++) {
                    short8 b = *(const short8*)(bp + (long)t * 16 * 512 + ks * 32);
                    s[0][t] = __builtin_amdgcn_mfma_f32_16x16x32_bf16(a0, b, s[0][t], 0, 0, 0);
                    s[1][t] = __builtin_amdgcn_mfma_f32_16x16x32_bf16(a1, b, s[1][t], 0, 0, 0);
                }
            }

            // exp (|logit| <= max|kq| ~ 5.6), P write, row-sum partials
            float psum[2][4];
#pragma unroll
            for (int qt = 0; qt < 2; qt++)
#pragma unroll
                for (int r = 0; r < 4; r++) psum[qt][r] = 0.f;
#pragma unroll
            for (int t = 0; t < 4; t++)
#pragma unroll
                for (int qt = 0; qt < 2; qt++)
#pragma unroll
                    for (int r = 0; r < 4; r++) {
                        float e = __expf(s[qt][t][r]);
                        psum[qt][r] += e;
                        P[(qt * 16 + rq + r) * LDP + m0 + t * 16 + rl] = f2b(e);
                    }
            for (int d = 1; d < 16; d <<= 1)
#pragma unroll
                for (int qt = 0; qt < 2; qt++)
#pragma unroll
                    for (int r = 0; r < 4; r++) psum[qt][r] += __shfl_xor(psum[qt][r], d);
            if (rl == 0)
#pragma unroll
                for (int qt = 0; qt < 2; qt++)
#pragma unroll
                    for (int r = 0; r < 4; r++)
                        atomicAdd(&lcur[qt * 16 + rq + r], psum[qt][r]);
        }
        if (tid < 32) lnxt[tid] = 0.f;   // prep next head's l buffer
        __syncthreads();

        // ---- normalize P in place (l complete) ----
#pragma unroll
        for (int i = 0; i < 4; i++) {
            int c = tid + i * 1024;       // 4096 chunks of 8 (32 rows x 128)
            int r = c >> 7, cc = (c & 127) * 8;
            float inv = 1.f / lcur[r];
            u16* pp = &P[r * LDP + cc];
            short8 v = *(short8*)pp;
            u16 o[8];
#pragma unroll
            for (int q = 0; q < 8; q++) o[q] = f2b(b2f(((u16*)&v)[q]) * inv);
            *(short8*)pp = *(short8*)o;
        }
        __syncthreads();

        // ---- PV phase: wave owns o-cols [wid*32, +32) ----
        {
            const u16* vb0 = vph + (long)(wid * 32 + rl) * Mm + gl8;
            const u16* vb1 = vph + (long)(wid * 32 + 16 + rl) * Mm + gl8;
#pragma unroll 4
            for (int mk = 0; mk < 32; mk++) {
                short8 a0 = *(const short8*)&P[rl * LDP + mk * 32 + gl8];
                short8 a1 = *(const short8*)&P[(16 + rl) * LDP + mk * 32 + gl8];
                short8 b0 = *(const short8*)(vb0 + mk * 32);
                short8 b1 = *(const short8*)(vb1 + mk * 32);
                oacc[0][0] = __builtin_amdgcn_mfma_f32_16x16x32_bf16(a0, b0, oacc[0][0], 0, 0, 0);
                oacc[0][1] = __builtin_amdgcn_mfma_f32_16x16x32_bf16(a0, b1, oacc[0][1], 0, 0, 0);
                oacc[1][0] = __builtin_amdgcn_mfma_f32_16x16x32_bf16(a1, b0, oacc[1][0], 0, 0, 0);
                oacc[1][1] = __builtin_amdgcn_mfma_f32_16x16x32_bf16(a1, b1, oacc[1][1], 0, 0, 0);
            }
        }
        __syncthreads();   // P reads done before next head's S overwrites
    }

    // epilogue: out[n][col] = oacc + bf[col]  (fp32 store)
#pragma unroll
    for (int qt = 0; qt < 2; qt++)
#pragma unroll
        for (int ot = 0; ot < 2; ot++) {
            int col = wid * 32 + ot * 16 + rl;
            float add = bfv[col];
#pragma unroll
            for (int r = 0; r < 4; r++) {
                int row = n0 + qt * 16 + rq + r;
                out[(long)row * 512 + col] = oacc[qt][ot][r] + add;
            }
        }
}

// ---------------------------------------------------------------------------
extern "C" void kernel_launch(void* const* d_in, const int* in_sizes, int n_in,
                              void* d_out, int out_size, void* d_ws, size_t ws_size,
                              hipStream_t stream)
{
    const float* k    = (const float*)d_in[0];   // [N][O] fp32
    const void*  mems = d_in[1];                 // [H][M][D] fp32
    const void*  Wk   = d_in[2];                 // [H][O][D] fp32
    const float* bk   = (const float*)d_in[3];   // [H][O] fp32
    const void*  Wv   = d_in[4];                 // [H][O][D] fp32
    const float* bv   = (const float*)d_in[5];   // [H][O] fp32
    const void*  Wf   = d_in[6];                 // [O][H*O] fp32
    const float* bfv  = (const float*)d_in[7];   // [O] fp32
    float* out = (float*)d_out;

    char* ws = (char*)d_ws;
    float* logits = (float*)ws;                                   // H*M*O fp32 = 32 MB
    u16* keyb = (u16*)(ws + (size_t)Hh * Mm * Oo * 4);            // H*M*O bf16 = 16 MB
    u16* valb = keyb + (size_t)Hh * Mm * Oo;                      // 16 MB
    u16* vptb = valb + (size_t)Hh * Mm * Oo;                      // V'^T [H][O][M], 16 MB

    // key logits: [h][m][o] = mems_h @ Wk_h^T + bk_h   (fp32 out)
    gemm_bt<<<dim3(8, 16, 16), 256, 0, stream>>>(
        mems, Wk, bk, logits, 512, 512, 512, 512,
        (long)Mm * Dd, (long)Oo * Dd, 512L, (long)Mm * Oo, 1, 1, 0);

    // mem_key = softmax(logits) -> bf16
    softmax_rows<<<dim3(Hh * Mm / 4), 256, 0, stream>>>(logits, keyb);

    // val: [h][m][o] = mems_h @ Wv_h^T + bv_h   (bf16 out)
    gemm_bt<<<dim3(8, 16, 16), 256, 0, stream>>>(
        mems, Wv, bv, valb, 512, 512, 512, 512,
        (long)Mm * Dd, (long)Oo * Dd, 512L, (long)Mm * Oo, 1, 1, 1);

    // V'^T: [h][o][m] = Wf[:, h*O:(h+1)*O] @ val_h^T   (bf16 out, transposed)
    gemm_bt<<<dim3(16, 8, 16), 256, 0, stream>>>(
        Wf, valb, nullptr, vptb, 512, Hh * Oo, 512, 1024,
        512L, (long)Mm * Oo, 0L, (long)Oo * Mm, 1, 0, 1);

    // fused attention over all heads, final projection pre-folded into V'
    flash<<<dim3(Nn / 32), 1024, FLASH_LDS, stream>>>(k, keyb, vptb, bfv, out);
}